// Round 1
// baseline (282.205 us; speedup 1.0000x reference)
//
#include <hip/hip_runtime.h>

// CP-rank-32 tensor reconstruction: out[i,j,k] = sum_r W0[i,r]*W1[j,r]*W2[k,r]
// Shapes: W0 256x32, W1 256x32, W2 1024x32, out 256x256x1024 fp32 (268 MB).
// Write-BW-bound: ~45 us floor at ~6 TB/s. Compute (4.3 GFLOP fp32) ~27 us, hidden.

constexpr int I_DIM = 256;
constexpr int J_DIM = 256;
constexpr int K_DIM = 1024;
constexpr int RNK   = 32;
constexpr int JT    = 16;   // j-tile per block

__device__ __forceinline__ void fma4(float4& a, float s, const float4& v) {
    a.x = fmaf(s, v.x, a.x);
    a.y = fmaf(s, v.y, a.y);
    a.z = fmaf(s, v.z, a.z);
    a.w = fmaf(s, v.w, a.w);
}

// W2 (1024x32, row-major) -> W2T (32x1024) so main-loop loads are coalesced in k.
__global__ void transpose_w2(const float* __restrict__ W2, float* __restrict__ W2T) {
    int idx = blockIdx.x * 256 + threadIdx.x;   // 0 .. 32767
    int r = idx >> 10;
    int k = idx & (K_DIM - 1);
    W2T[r * K_DIM + k] = W2[k * RNK + r];
}

// Main kernel, transposed-W2 path. Block: one i, JT j's, all 1024 k (thread = 4 k's).
__global__ __launch_bounds__(256, 4) void cp_recon_t(const float* __restrict__ W0,
                                                     const float* __restrict__ W1,
                                                     const float* __restrict__ W2T,
                                                     float* __restrict__ out) {
    __shared__ __align__(16) float c[JT][RNK];
    const int i     = blockIdx.x >> 4;          // / (J_DIM/JT)
    const int jbase = (blockIdx.x & 15) * JT;
    const int tid   = threadIdx.x;

    // c[j][r] = W0[i,r] * W1[jbase+j, r]  (block-uniform, 512 floats)
    for (int idx = tid; idx < JT * RNK; idx += 256) {
        int jj = idx >> 5;
        int r  = idx & 31;
        c[jj][r] = W0[i * RNK + r] * W1[(jbase + jj) * RNK + r];
    }
    __syncthreads();

    const int k = tid * 4;
    float4 acc[JT];
#pragma unroll
    for (int jj = 0; jj < JT; ++jj) acc[jj] = make_float4(0.f, 0.f, 0.f, 0.f);

#pragma unroll 2
    for (int rc = 0; rc < RNK; rc += 4) {
        float4 w[4];
#pragma unroll
        for (int q = 0; q < 4; ++q)
            w[q] = *reinterpret_cast<const float4*>(&W2T[(rc + q) * K_DIM + k]);
#pragma unroll
        for (int jj = 0; jj < JT; ++jj) {
            float4 c4 = *reinterpret_cast<const float4*>(&c[jj][rc]);  // broadcast
            fma4(acc[jj], c4.x, w[0]);
            fma4(acc[jj], c4.y, w[1]);
            fma4(acc[jj], c4.z, w[2]);
            fma4(acc[jj], c4.w, w[3]);
        }
    }

#pragma unroll
    for (int jj = 0; jj < JT; ++jj) {
        int o = (i * J_DIM + jbase + jj) * K_DIM + k;
        *reinterpret_cast<float4*>(&out[o]) = acc[jj];
    }
}

// Fallback (no workspace): read W2 rows directly (per-thread, cached).
__global__ __launch_bounds__(256, 4) void cp_recon_d(const float* __restrict__ W0,
                                                     const float* __restrict__ W1,
                                                     const float* __restrict__ W2,
                                                     float* __restrict__ out) {
    __shared__ __align__(16) float c[JT][RNK];
    const int i     = blockIdx.x >> 4;
    const int jbase = (blockIdx.x & 15) * JT;
    const int tid   = threadIdx.x;

    for (int idx = tid; idx < JT * RNK; idx += 256) {
        int jj = idx >> 5;
        int r  = idx & 31;
        c[jj][r] = W0[i * RNK + r] * W1[(jbase + jj) * RNK + r];
    }
    __syncthreads();

    const int k = tid * 4;
    float4 acc[JT];
#pragma unroll
    for (int jj = 0; jj < JT; ++jj) acc[jj] = make_float4(0.f, 0.f, 0.f, 0.f);

    for (int rc = 0; rc < RNK; rc += 4) {
        float4 row[4];  // row[q] = W2[k+q, rc..rc+3]
#pragma unroll
        for (int q = 0; q < 4; ++q)
            row[q] = *reinterpret_cast<const float4*>(&W2[(k + q) * RNK + rc]);
#pragma unroll
        for (int jj = 0; jj < JT; ++jj) {
            float4 c4 = *reinterpret_cast<const float4*>(&c[jj][rc]);
            acc[jj].x = fmaf(c4.x, row[0].x, fmaf(c4.y, row[0].y, fmaf(c4.z, row[0].z, fmaf(c4.w, row[0].w, acc[jj].x))));
            acc[jj].y = fmaf(c4.x, row[1].x, fmaf(c4.y, row[1].y, fmaf(c4.z, row[1].z, fmaf(c4.w, row[1].w, acc[jj].y))));
            acc[jj].z = fmaf(c4.x, row[2].x, fmaf(c4.y, row[2].y, fmaf(c4.z, row[2].z, fmaf(c4.w, row[2].w, acc[jj].z))));
            acc[jj].w = fmaf(c4.x, row[3].x, fmaf(c4.y, row[3].y, fmaf(c4.z, row[3].z, fmaf(c4.w, row[3].w, acc[jj].w))));
        }
    }

#pragma unroll
    for (int jj = 0; jj < JT; ++jj) {
        int o = (i * J_DIM + jbase + jj) * K_DIM + k;
        *reinterpret_cast<float4*>(&out[o]) = acc[jj];
    }
}

extern "C" void kernel_launch(void* const* d_in, const int* in_sizes, int n_in,
                              void* d_out, int out_size, void* d_ws, size_t ws_size,
                              hipStream_t stream) {
    const float* W0 = (const float*)d_in[0];
    const float* W1 = (const float*)d_in[1];
    const float* W2 = (const float*)d_in[2];
    float* out = (float*)d_out;

    const int grid = I_DIM * (J_DIM / JT);  // 4096 blocks

    if (ws_size >= (size_t)(RNK * K_DIM) * sizeof(float)) {
        float* W2T = (float*)d_ws;
        transpose_w2<<<(RNK * K_DIM) / 256, 256, 0, stream>>>(W2, W2T);
        cp_recon_t<<<grid, 256, 0, stream>>>(W0, W1, W2T, out);
    } else {
        cp_recon_d<<<grid, 256, 0, stream>>>(W0, W1, W2, out);
    }
}

// Round 3
// 83.501 us; speedup vs baseline: 3.3797x; 3.3797x over previous
//
#include <hip/hip_runtime.h>

// CP-rank-32 tensor reconstruction: out[i,j,k] = sum_r W0[i,r]*W1[j,r]*W2[k,r]
// Shapes: W0 256x32, W1 256x32, W2 1024x32, out 256x256x1024 fp32 (268 MB).
// Write-BW-bound: floor ~45-65 us. R1 lesson: JT=16 -> acc[16] float4 = 64 VGPRs
// spilled to scratch (FETCH 84MB, WRITE 893MB, 282us). JT=8 keeps acc in regs.
// R2 lesson: __builtin_nontemporal_store needs a native vector type, not float4.

constexpr int I_DIM = 256;
constexpr int J_DIM = 256;
constexpr int K_DIM = 1024;
constexpr int RNK   = 32;
constexpr int JT    = 8;    // j-tile per block: acc[8] float4 = 32 VGPRs, no spill

typedef float f32x4 __attribute__((ext_vector_type(4)));

__device__ __forceinline__ void fma4(float4& a, float s, const float4& v) {
    a.x = fmaf(s, v.x, a.x);
    a.y = fmaf(s, v.y, a.y);
    a.z = fmaf(s, v.z, a.z);
    a.w = fmaf(s, v.w, a.w);
}

__device__ __forceinline__ void store_nt4(float* p, const float4& v) {
    f32x4 t = { v.x, v.y, v.z, v.w };
    __builtin_nontemporal_store(t, reinterpret_cast<f32x4*>(p));
}

// W2 (1024x32, row-major) -> W2T (32x1024) so main-loop loads are coalesced in k.
__global__ void transpose_w2(const float* __restrict__ W2, float* __restrict__ W2T) {
    int idx = blockIdx.x * 256 + threadIdx.x;   // 0 .. 32767
    int r = idx >> 10;
    int k = idx & (K_DIM - 1);
    W2T[r * K_DIM + k] = W2[k * RNK + r];
}

// Block: one i, JT j's, all 1024 k (thread = 4 consecutive k's).
__global__ __launch_bounds__(256, 4) void cp_recon_t(const float* __restrict__ W0,
                                                     const float* __restrict__ W1,
                                                     const float* __restrict__ W2T,
                                                     float* __restrict__ out) {
    __shared__ __align__(16) float c[JT][RNK];
    const int i     = blockIdx.x >> 5;            // / (J_DIM/JT)
    const int jbase = (blockIdx.x & 31) * JT;
    const int tid   = threadIdx.x;

    // c[j][r] = W0[i,r] * W1[jbase+j, r]  (block-uniform, JT*32 floats)
    if (tid < JT * RNK) {
        int jj = tid >> 5;
        int r  = tid & 31;
        c[jj][r] = W0[i * RNK + r] * W1[(jbase + jj) * RNK + r];
    }
    __syncthreads();

    const int k = tid * 4;
    float4 acc[JT];
#pragma unroll
    for (int jj = 0; jj < JT; ++jj) acc[jj] = make_float4(0.f, 0.f, 0.f, 0.f);

#pragma unroll 2
    for (int rc = 0; rc < RNK; rc += 4) {
        float4 w[4];
#pragma unroll
        for (int q = 0; q < 4; ++q)
            w[q] = *reinterpret_cast<const float4*>(&W2T[(rc + q) * K_DIM + k]);
#pragma unroll
        for (int jj = 0; jj < JT; ++jj) {
            float4 c4 = *reinterpret_cast<const float4*>(&c[jj][rc]);  // LDS broadcast
            fma4(acc[jj], c4.x, w[0]);
            fma4(acc[jj], c4.y, w[1]);
            fma4(acc[jj], c4.z, w[2]);
            fma4(acc[jj], c4.w, w[3]);
        }
    }

    // Streaming output, never re-read; out (268MB) > LLC (256MB) -> nontemporal.
#pragma unroll
    for (int jj = 0; jj < JT; ++jj) {
        int o = (i * J_DIM + jbase + jj) * K_DIM + k;
        store_nt4(&out[o], acc[jj]);
    }
}

// Fallback (no workspace): read W2 rows directly (per-thread, cached).
__global__ __launch_bounds__(256, 4) void cp_recon_d(const float* __restrict__ W0,
                                                     const float* __restrict__ W1,
                                                     const float* __restrict__ W2,
                                                     float* __restrict__ out) {
    __shared__ __align__(16) float c[JT][RNK];
    const int i     = blockIdx.x >> 5;
    const int jbase = (blockIdx.x & 31) * JT;
    const int tid   = threadIdx.x;

    if (tid < JT * RNK) {
        int jj = tid >> 5;
        int r  = tid & 31;
        c[jj][r] = W0[i * RNK + r] * W1[(jbase + jj) * RNK + r];
    }
    __syncthreads();

    const int k = tid * 4;
    float4 acc[JT];
#pragma unroll
    for (int jj = 0; jj < JT; ++jj) acc[jj] = make_float4(0.f, 0.f, 0.f, 0.f);

    for (int rc = 0; rc < RNK; rc += 4) {
        float4 row[4];  // row[q] = W2[k+q, rc..rc+3]
#pragma unroll
        for (int q = 0; q < 4; ++q)
            row[q] = *reinterpret_cast<const float4*>(&W2[(k + q) * RNK + rc]);
#pragma unroll
        for (int jj = 0; jj < JT; ++jj) {
            float4 c4 = *reinterpret_cast<const float4*>(&c[jj][rc]);
            acc[jj].x = fmaf(c4.x, row[0].x, fmaf(c4.y, row[0].y, fmaf(c4.z, row[0].z, fmaf(c4.w, row[0].w, acc[jj].x))));
            acc[jj].y = fmaf(c4.x, row[1].x, fmaf(c4.y, row[1].y, fmaf(c4.z, row[1].z, fmaf(c4.w, row[1].w, acc[jj].y))));
            acc[jj].z = fmaf(c4.x, row[2].x, fmaf(c4.y, row[2].y, fmaf(c4.z, row[2].z, fmaf(c4.w, row[2].w, acc[jj].z))));
            acc[jj].w = fmaf(c4.x, row[3].x, fmaf(c4.y, row[3].y, fmaf(c4.z, row[3].w, fmaf(c4.w, row[3].w, acc[jj].w))));
        }
    }

#pragma unroll
    for (int jj = 0; jj < JT; ++jj) {
        int o = (i * J_DIM + jbase + jj) * K_DIM + k;
        store_nt4(&out[o], acc[jj]);
    }
}

extern "C" void kernel_launch(void* const* d_in, const int* in_sizes, int n_in,
                              void* d_out, int out_size, void* d_ws, size_t ws_size,
                              hipStream_t stream) {
    const float* W0 = (const float*)d_in[0];
    const float* W1 = (const float*)d_in[1];
    const float* W2 = (const float*)d_in[2];
    float* out = (float*)d_out;

    const int grid = I_DIM * (J_DIM / JT);  // 8192 blocks

    if (ws_size >= (size_t)(RNK * K_DIM) * sizeof(float)) {
        float* W2T = (float*)d_ws;
        transpose_w2<<<(RNK * K_DIM) / 256, 256, 0, stream>>>(W2, W2T);
        cp_recon_t<<<grid, 256, 0, stream>>>(W0, W1, W2T, out);
    } else {
        cp_recon_d<<<grid, 256, 0, stream>>>(W0, W1, W2, out);
    }
}